// Round 7
// baseline (245.722 us; speedup 1.0000x reference)
//
#include <hip/hip_runtime.h>
#include <math.h>

#define DIM   256
#define NLVL  5
#define NB1   2048           // pass1 blocks (8192 waves)
#define NW1   (NB1*4)

struct Ptrs {
  const float* p[NLVL];
  const float* W[NLVL];
  const float* b[NLVL];
};

// ---- pass 1: all 5 levels per row, depth-2 two-slot register pipeline.
//      __launch_bounds__(256,2): min 2 waves/EU -> 128-VGPR budget so the
//      10 float4 payloads are genuinely co-resident (R4 failed at 64-VGPR target).
__global__ __launch_bounds__(256, 2) void k_pass1(Ptrs pt, float* __restrict__ logits,
                                                  float2* __restrict__ part, int N)
{
  const int lane = threadIdx.x & 63;
  const int wid  = threadIdx.x >> 6;

  float4 wf[NLVL];
  float  bias[NLVL], m[NLVL], s[NLVL];
  #pragma unroll
  for (int l = 0; l < NLVL; l++) {
    wf[l]   = *reinterpret_cast<const float4*>(pt.W[l] + lane * 4);
    bias[l] = *pt.b[l];
    m[l]    = -INFINITY;
    s[l]    = 0.f;
  }

  const int gw  = blockIdx.x * 4 + wid;        // 0..8191
  const int off = lane * 4;

  float4 A0, A1, A2, A3, A4;                   // slot A payload (row i)
  float4 B0, B1, B2, B3, B4;                   // slot B payload (row i+NW1)

#define LOADSLOT(S0_,S1_,S2_,S3_,S4_, idx)                                          \
  do { size_t n_ = ((idx) < N) ? (size_t)(idx) : 0;                                 \
    S0_ = *reinterpret_cast<const float4*>(pt.p[0] + n_ * DIM + off);               \
    S1_ = *reinterpret_cast<const float4*>(pt.p[1] + n_ * DIM + off);               \
    S2_ = *reinterpret_cast<const float4*>(pt.p[2] + n_ * DIM + off);               \
    S3_ = *reinterpret_cast<const float4*>(pt.p[3] + n_ * DIM + off);               \
    S4_ = *reinterpret_cast<const float4*>(pt.p[4] + n_ * DIM + off);               \
  } while (0)

#define CONSUME(S0_,S1_,S2_,S3_,S4_, row)                                           \
  do {                                                                              \
    float d[NLVL];                                                                  \
    d[0] = S0_.x*wf[0].x + S0_.y*wf[0].y + S0_.z*wf[0].z + S0_.w*wf[0].w;           \
    d[1] = S1_.x*wf[1].x + S1_.y*wf[1].y + S1_.z*wf[1].z + S1_.w*wf[1].w;           \
    d[2] = S2_.x*wf[2].x + S2_.y*wf[2].y + S2_.z*wf[2].z + S2_.w*wf[2].w;           \
    d[3] = S3_.x*wf[3].x + S3_.y*wf[3].y + S3_.z*wf[3].z + S3_.w*wf[3].w;           \
    d[4] = S4_.x*wf[4].x + S4_.y*wf[4].y + S4_.z*wf[4].z + S4_.w*wf[4].w;           \
    _Pragma("unroll")                                                               \
    for (int o_ = 32; o_; o_ >>= 1) {                                               \
      _Pragma("unroll")                                                             \
      for (int l_ = 0; l_ < NLVL; l_++) d[l_] += __shfl_xor(d[l_], o_);             \
    }                                                                               \
    _Pragma("unroll")                                                               \
    for (int l_ = 0; l_ < NLVL; l_++) d[l_] += bias[l_];                            \
    float sv = d[0];                                                                \
    sv = (lane == 1) ? d[1] : sv;                                                   \
    sv = (lane == 2) ? d[2] : sv;                                                   \
    sv = (lane == 3) ? d[3] : sv;                                                   \
    sv = (lane == 4) ? d[4] : sv;                                                   \
    if (lane < NLVL) logits[(size_t)lane * N + (row)] = sv;                         \
    _Pragma("unroll")                                                               \
    for (int l_ = 0; l_ < NLVL; l_++) {                                             \
      float Mn = fmaxf(m[l_], d[l_]);                                               \
      s[l_] = s[l_] * __expf(m[l_] - Mn) + __expf(d[l_] - Mn);                      \
      m[l_] = Mn;                                                                   \
    }                                                                               \
  } while (0)

  // prologue: fill both slots
  LOADSLOT(A0,A1,A2,A3,A4, gw);
  LOADSLOT(B0,B1,B2,B3,B4, gw + NW1);
  __builtin_amdgcn_sched_barrier(0);

  for (int i = gw; i < N; i += 2 * NW1) {
    CONSUME(A0,A1,A2,A3,A4, i);                // row i (always valid)
    LOADSLOT(A0,A1,A2,A3,A4, i + 2 * NW1);     // refill A (clamped)
    __builtin_amdgcn_sched_barrier(0);
    if (i + NW1 < N) {                         // wave-uniform branch
      CONSUME(B0,B1,B2,B3,B4, i + NW1);
    }
    LOADSLOT(B0,B1,B2,B3,B4, i + 3 * NW1);     // refill B (clamped)
    __builtin_amdgcn_sched_barrier(0);
  }
#undef LOADSLOT
#undef CONSUME

  __shared__ float smM[4][NLVL], smS[4][NLVL];
  if (lane == 0) {
    #pragma unroll
    for (int l = 0; l < NLVL; l++) { smM[wid][l] = m[l]; smS[wid][l] = s[l]; }
  }
  __syncthreads();
  if (threadIdx.x < NLVL) {
    const int l = threadIdx.x;
    float M = smM[0][l], S = smS[0][l];
    #pragma unroll
    for (int i = 1; i < 4; i++) {
      float Mn = fmaxf(M, smM[i][l]);
      if (Mn > -INFINITY) { S = S * __expf(M - Mn) + smS[i][l] * __expf(smM[i][l] - Mn); M = Mn; }
    }
    part[l * NB1 + blockIdx.x] = make_float2(M, S);
  }
}

// ---- combine NB1 partials per level -> (M, S) ----
__global__ __launch_bounds__(320) void k_reduce(const float2* __restrict__ part,
                                                float2* __restrict__ stats)
{
  const int lvl  = threadIdx.x >> 6;
  const int lane = threadIdx.x & 63;
  float m = -INFINITY, s = 0.f;
  for (int i = lane; i < NB1; i += 64) {
    float2 ps = part[lvl * NB1 + i];
    float Mn = fmaxf(m, ps.x);
    if (Mn > -INFINITY) { s = s * __expf(m - Mn) + ps.y * __expf(ps.x - Mn); m = Mn; }
  }
  #pragma unroll
  for (int o = 32; o; o >>= 1) {
    float mo = __shfl_xor(m, o), so = __shfl_xor(s, o);
    float Mn = fmaxf(m, mo);
    if (Mn > -INFINITY) { s = s * __expf(m - Mn) + so * __expf(mo - Mn); m = Mn; }
  }
  if (lane == 0) stats[lvl] = make_float2(m, s);
}

// ---- pass 2: weights + fused output ----
__global__ __launch_bounds__(256) void k_pass2(Ptrs pt, const float* __restrict__ logits,
                                               const float2* __restrict__ stats,
                                               float* __restrict__ out, int N)
{
  const int lane = threadIdx.x & 63;
  const int wid  = threadIdx.x >> 6;
  float M[NLVL], Si[NLVL];
  #pragma unroll
  for (int l = 0; l < NLVL; l++) { float2 st = stats[l]; M[l] = st.x; Si[l] = 1.f / st.y; }

  const int gw = blockIdx.x * 4 + wid;
  const int nw = gridDim.x * 4;
  for (int n = gw; n < N; n += nw) {
    float wl[NLVL], t = 0.f;
    #pragma unroll
    for (int l = 0; l < NLVL; l++) {
      float e = __expf(logits[(size_t)l * N + n] - M[l]) * Si[l];
      wl[l] = e; t += e;
    }
    const float inv = 1.f / t;
    float4 acc = make_float4(0.f, 0.f, 0.f, 0.f);
    #pragma unroll
    for (int l = 0; l < NLVL; l++) {
      float4 pv = *reinterpret_cast<const float4*>(pt.p[l] + (size_t)n * DIM + lane * 4);
      float c = wl[l] * inv;
      acc.x += c * pv.x; acc.y += c * pv.y; acc.z += c * pv.z; acc.w += c * pv.w;
    }
    *reinterpret_cast<float4*>(out + (size_t)n * DIM + lane * 4) = acc;
  }
}

extern "C" void kernel_launch(void* const* d_in, const int* in_sizes, int n_in,
                              void* d_out, int out_size, void* d_ws, size_t ws_size,
                              hipStream_t stream)
{
  Ptrs pt;
  for (int l = 0; l < NLVL; l++) {
    pt.p[l] = (const float*)d_in[l];
    pt.W[l] = (const float*)d_in[5 + 2 * l];
    pt.b[l] = (const float*)d_in[6 + 2 * l];
  }
  const int N = in_sizes[0] / DIM;             // 100000

  char* ws = (char*)d_ws;
  size_t logits_bytes = ((size_t)NLVL * N * sizeof(float) + 255) & ~(size_t)255;
  float*  logits = (float*)ws;
  float2* part   = (float2*)(ws + logits_bytes);
  float2* stats  = part + NLVL * NB1;

  k_pass1 <<<NB1,  256, 0, stream>>>(pt, logits, part, N);
  k_reduce<<<1,    320, 0, stream>>>(part, stats);
  k_pass2 <<<2048, 256, 0, stream>>>(pt, logits, stats, (float*)d_out, N);
}